// Round 6
// baseline (791.859 us; speedup 1.0000x reference)
//
#include <hip/hip_runtime.h>

#define TT 4
#define BB 16
#define VV 128
#define EE 512
#define HIDC 2048
#define BN_EPS 1e-5f

typedef unsigned int u32;
typedef unsigned long long u64;
typedef unsigned short u16;
typedef unsigned char u8;

// ---------------- all-layer weight transpose: WT[c][o] ----------------
__global__ __launch_bounds__(256) void trans_all(const float* __restrict__ qw,
    const float* __restrict__ f1w, const float* __restrict__ f2w,
    float* __restrict__ wq, float* __restrict__ w1, float* __restrict__ w2)
{
  const int d = blockIdx.z, zz = blockIdx.y;
  const float* src; float* dst; int O, C;
  if (zz < 4)      { src = qw + ((size_t)d * 4 + zz) * EE * EE; dst = wq + ((size_t)d * 4 + zz) * EE * EE; O = EE; C = EE; }
  else if (zz == 4){ src = f1w + (size_t)d * HIDC * EE; dst = w1 + (size_t)d * HIDC * EE; O = HIDC; C = EE; }
  else             { src = f2w + (size_t)d * EE * HIDC; dst = w2 + (size_t)d * EE * HIDC; O = EE; C = HIDC; }
  const int tc_n = C >> 5, to_n = O >> 5;
  const int bx = blockIdx.x;
  if (bx >= tc_n * to_n) return;
  const int tc = bx % tc_n, to = bx / tc_n;
  __shared__ float t[32][33];
  const int tx = threadIdx.x & 31, ty = threadIdx.x >> 5;
#pragma unroll
  for (int k = 0; k < 4; ++k) {
    int o = to * 32 + ty + k * 8, c = tc * 32 + tx;
    t[ty + k * 8][tx] = src[(size_t)o * C + c];
  }
  __syncthreads();
#pragma unroll
  for (int k = 0; k < 4; ++k) {
    int c = tc * 32 + ty + k * 8, o = to * 32 + tx;
    dst[(size_t)c * O + o] = t[tx][ty + k * 8];
  }
}

// ---------------- patch embed + BN + LIF -> h + masks + slot lists ----------------
// grid (B, E/16); thread owns 8 v's of channel ch = by*16 + (tid>>4).
__global__ __launch_bounds__(256) void pe_lif(const float* __restrict__ x,
    const float* __restrict__ w, const float* __restrict__ bnp,
    float* __restrict__ h, u32* __restrict__ mIn,
    u32* __restrict__ cnt, u16* __restrict__ ids)
{
  const int b = blockIdx.x, eb = blockIdx.y;
  const int tid = threadIdx.x;
  const int chl = tid >> 4, e = eb * 16 + chl;
  const int vs = (tid & 15) * 8;
  __shared__ u8 sB[16][16];
  __shared__ u8 sAct[16];
  const float w0 = w[e * 2], w1 = w[e * 2 + 1];
  const float gg = bnp[e], be = bnp[EE + e], mm = bnp[2 * EE + e], vr = bnp[3 * EE + e];
  const float sc = gg / sqrtf(vr + BN_EPS);
  float vm[8];
#pragma unroll
  for (int k = 0; k < 8; ++k) vm[k] = 0.f;
  for (int t = 0; t < TT; ++t) {
    const int tb = t * BB + b;
    const float* xb = x + (size_t)tb * 2 * VV + vs;
    float4 x0a = *(const float4*)&xb[0],   x0b = *(const float4*)&xb[4];
    float4 x1a = *(const float4*)&xb[VV],  x1b = *(const float4*)&xb[VV + 4];
    float a[8] = {x0a.x, x0a.y, x0a.z, x0a.w, x0b.x, x0b.y, x0b.z, x0b.w};
    float c1[8] = {x1a.x, x1a.y, x1a.z, x1a.w, x1b.x, x1b.y, x1b.z, x1b.w};
    u32 byte = 0;
#pragma unroll
    for (int k = 0; k < 8; ++k) {
      a[k] = (w0 * a[k] + w1 * c1[k] - mm) * sc + be;
      vm[k] += (a[k] - vm[k]) * 0.5f;
      float sp = (vm[k] >= 1.f) ? 1.f : 0.f;
      vm[k] *= (1.f - sp);
      byte |= (sp != 0.f) ? (1u << k) : 0u;
    }
    size_t ho = ((size_t)tb * EE + e) * VV + vs;
    float4 ha = {a[0], a[1], a[2], a[3]}, hb = {a[4], a[5], a[6], a[7]};
    *(float4*)&h[ho] = ha; *(float4*)&h[ho + 4] = hb;
    sB[chl][tid & 15] = (u8)byte;
    __syncthreads();
    if (tid < 16) {
      uint4 mw = *(const uint4*)&sB[tid][0];
      *(uint4*)&mIn[((size_t)tb * EE + eb * 16 + tid) * 4] = mw;
      sAct[tid] = (mw.x | mw.y | mw.z | mw.w) ? 1 : 0;
    }
    __syncthreads();
    if (tid == 0) {
      int c = 0;
      for (int i = 0; i < 16; ++i)
        if (sAct[i]) ids[((size_t)tb * 32 + eb) * 16 + c++] = (u16)(eb * 16 + i);
      cnt[(size_t)tb * 32 + eb] = c;
    }
    __syncthreads();
  }
}

// ---------------- sparse bit-spike GEMM (no LDS staging), slot lists in/out ----------------
// grid (B, O/16, nz), 256 thr. Thread: 2 o x 4 v. K-loop streams WT/masks from L2.
__global__ __launch_bounds__(256) void gemm_fused(
    const u32* __restrict__ InM, const u32* __restrict__ cntI,
    const u16* __restrict__ idsI, int nblkI,
    const float* __restrict__ WT, float* __restrict__ OutPre,
    const float* __restrict__ resid, u32* __restrict__ SpkM,
    u32* __restrict__ cntO, u16* __restrict__ idsO,
    const float* __restrict__ bias, const float* __restrict__ bn1,
    const float* __restrict__ bn2,
    int C, int O, float vth, long wtZ, long spkZ, long bnZ)
{
  const int b = blockIdx.x, ob = blockIdx.y * 16, z = blockIdx.z;
  const int tid = threadIdx.x;
  WT += (long)z * wtZ; SpkM += (long)z * spkZ;
  if (bn1) bn1 += (long)z * bnZ;
  if (bn2) bn2 += (long)z * bnZ;

  __shared__ u16 slist[2048];
  __shared__ u32 scnt[128], soff[128], runb;
  __shared__ u8 sAct[16];

  const int og = (tid >> 5) * 2;
  const bool hasb = (bias != nullptr), has1 = (bn1 != nullptr), has2 = (bn2 != nullptr);

  float bs[2], m1c[2], s1c[2], b1c[2], m2c[2], s2c[2], b2c[2];
#pragma unroll
  for (int j = 0; j < 2; ++j) {
    int o = ob + og + j;
    bs[j] = hasb ? bias[o] : 0.f;
    if (has1) { float g = bn1[o]; b1c[j] = bn1[O + o]; m1c[j] = bn1[2 * O + o];
                s1c[j] = g / sqrtf(bn1[3 * O + o] + BN_EPS); }
    if (has2) { float g = bn2[o]; b2c[j] = bn2[O + o]; m2c[j] = bn2[2 * O + o];
                s2c[j] = g / sqrtf(bn2[3 * O + o] + BN_EPS); }
  }

  float st[2][4] = {};

  for (int t = 0; t < TT; ++t) {
    const int tb = t * BB + b;
    // ---- merge producer slot lists (ascending -> exact order) ----
    __syncthreads();
    if (tid < nblkI) scnt[tid] = cntI[(size_t)tb * nblkI + tid];
    __syncthreads();
    if (tid == 0) {
      u32 s = 0;
      for (int i = 0; i < nblkI; ++i) { soff[i] = s; s += scnt[i]; }
      runb = s;
    }
    __syncthreads();
    if (tid < nblkI) {
      u32 o = soff[tid], cn = scnt[tid];
      const u16* src = idsI + ((size_t)tb * nblkI + tid) * 16;
      for (u32 k = 0; k < cn; ++k) slist[o + k] = src[k];
    }
    __syncthreads();
    const int n = (int)runb;

    // ---- K loop: stream weights + mask words from cache ----
    float acc[2][4] = {};
    const u32* Mb = InM + (size_t)tb * C * 4 + ((tid & 31) >> 3);
    const float* Wb = WT + ob + og;
    const int sh4 = (tid & 7) * 4;
#pragma unroll 4
    for (int i = 0; i < n; ++i) {
      int c = slist[i];
      u32 mw = Mb[(size_t)c * 4];
      float2 w2 = *(const float2*)&Wb[(size_t)c * O];
      u32 nib = mw >> sh4;
      float i0 = (nib & 1u) ? 1.f : 0.f;
      float i1 = (nib & 2u) ? 1.f : 0.f;
      float i2 = (nib & 4u) ? 1.f : 0.f;
      float i3 = (nib & 8u) ? 1.f : 0.f;
      acc[0][0] += w2.x * i0; acc[0][1] += w2.x * i1;
      acc[0][2] += w2.x * i2; acc[0][3] += w2.x * i3;
      acc[1][0] += w2.y * i0; acc[1][1] += w2.y * i1;
      acc[1][2] += w2.y * i2; acc[1][3] += w2.y * i3;
    }

    // ---- epilogue: bias -> bn1 -> bn2 -> resid -> LIF -> masks + activity ----
#pragma unroll
    for (int j = 0; j < 2; ++j) {
      float a[4] = {acc[j][0], acc[j][1], acc[j][2], acc[j][3]};
      if (hasb) {
#pragma unroll
        for (int k = 0; k < 4; ++k) a[k] += bs[j];
      }
      if (has1) {
#pragma unroll
        for (int k = 0; k < 4; ++k) a[k] = (a[k] - m1c[j]) * s1c[j] + b1c[j];
      }
      if (has2) {
#pragma unroll
        for (int k = 0; k < 4; ++k) a[k] = (a[k] - m2c[j]) * s2c[j] + b2c[j];
      }
      size_t orow = (size_t)tb * O + ob + og + j;
      if (OutPre) {
        size_t oi = orow * VV + (tid & 31) * 4;
        float4 r = *(const float4*)&resid[oi];
        a[0] += r.x; a[1] += r.y; a[2] += r.z; a[3] += r.w;
        float4 wr = {a[0], a[1], a[2], a[3]};
        *(float4*)&OutPre[oi] = wr;
      }
      u32 nib = 0;
#pragma unroll
      for (int k = 0; k < 4; ++k) {
        st[j][k] += (a[k] - st[j][k]) * 0.5f;
        float sp = (st[j][k] >= vth) ? 1.f : 0.f;
        st[j][k] *= (1.f - sp);
        nib |= (sp != 0.f) ? (1u << k) : 0u;
      }
      u32 wmask = nib << sh4;
      wmask |= __shfl_xor(wmask, 1);
      wmask |= __shfl_xor(wmask, 2);
      wmask |= __shfl_xor(wmask, 4);
      if ((tid & 7) == 0) SpkM[orow * 4 + ((tid & 31) >> 3)] = wmask;
      u32 aw = wmask | __shfl_xor(wmask, 8);
      aw |= __shfl_xor(aw, 16);
      if ((tid & 31) == 0) sAct[(tid >> 5) * 2 + j] = aw ? 1 : 0;
    }
    if (cntO) {
      __syncthreads();
      if (tid == 0) {
        int c = 0;
        for (int i = 0; i < 16; ++i)
          if (sAct[i]) idsO[((size_t)tb * gridDim.y + blockIdx.y) * 16 + c++] = (u16)(ob + i);
        cntO[(size_t)tb * gridDim.y + blockIdx.y] = c;
      }
    }
  }
}

// ---------------- fused attention: KV=popcount(K&V); O=Q.KV*0.125; LIF(0.5) ----------------
// grid (B, 8 heads, 2 d-halves), 256 thr. Emits mO masks + slot lists.
__global__ __launch_bounds__(256) void attn_fused(const u32* __restrict__ Qm,
    const u32* __restrict__ Km, const u32* __restrict__ Vm, u32* __restrict__ Om,
    u32* __restrict__ cntO, u16* __restrict__ idsO)
{
  const int b = blockIdx.x, hh = blockIdx.y, dh = blockIdx.z;
  const int tid = threadIdx.x, lane = tid & 63;
  __shared__ float sQ[64][132];
  __shared__ float sKV[64][36];
  __shared__ u64 sKm[64][2], sQm[64][2], sVm[32][2];
  __shared__ u32 sQnz[64];
  __shared__ u8 sAct[32];
  const int np = lane * 2;
  const int dg = (tid >> 6) * 8;
  float st[8][2] = {};
  for (int t = 0; t < TT; ++t) {
    const int tb = t * BB + b;
    __syncthreads();
    if (tid < 64) {
      uint4 q = *(const uint4*)&Qm[((size_t)tb * EE + hh * 64 + tid) * 4];
      sQm[tid][0] = ((u64)q.y << 32) | q.x; sQm[tid][1] = ((u64)q.w << 32) | q.z;
      sQnz[tid] = q.x | q.y | q.z | q.w;
      uint4 k = *(const uint4*)&Km[((size_t)tb * EE + hh * 64 + tid) * 4];
      sKm[tid][0] = ((u64)k.y << 32) | k.x; sKm[tid][1] = ((u64)k.w << 32) | k.z;
    } else if (tid < 96) {
      int d = tid - 64;
      uint4 v = *(const uint4*)&Vm[((size_t)tb * EE + hh * 64 + dh * 32 + d) * 4];
      sVm[d][0] = ((u64)v.y << 32) | v.x; sVm[d][1] = ((u64)v.w << 32) | v.z;
    }
    __syncthreads();
    {
      int c = tid >> 2, dq = (tid & 3) * 8;
      u64 k0 = sKm[c][0], k1 = sKm[c][1];
#pragma unroll
      for (int i = 0; i < 8; ++i) {
        int d = dq + i;
        int p = __popcll(k0 & sVm[d][0]) + __popcll(k1 & sVm[d][1]);
        sKV[c][d] = (float)p;
      }
    }
    {
      int c = tid >> 2, nq = (tid & 3) * 32;
      u64 qw = sQm[c][nq >> 6] >> (nq & 32);
#pragma unroll
      for (int kk = 0; kk < 8; ++kk) {
        float4 f = {(qw >> (kk * 4)) & 1 ? 1.f : 0.f,
                    (qw >> (kk * 4 + 1)) & 1 ? 1.f : 0.f,
                    (qw >> (kk * 4 + 2)) & 1 ? 1.f : 0.f,
                    (qw >> (kk * 4 + 3)) & 1 ? 1.f : 0.f};
        *(float4*)&sQ[c][nq + kk * 4] = f;
      }
    }
    __syncthreads();
    float acc[8][2] = {};
    for (int c = 0; c < 64; ++c) {
      if (!sQnz[c]) continue;
      float2 q2 = *(const float2*)&sQ[c][np];
      float4 wa = *(const float4*)&sKV[c][dg];
      float4 wb = *(const float4*)&sKV[c][dg + 4];
      float w8[8] = {wa.x, wa.y, wa.z, wa.w, wb.x, wb.y, wb.z, wb.w};
#pragma unroll
      for (int i = 0; i < 8; ++i) { acc[i][0] += w8[i] * q2.x; acc[i][1] += w8[i] * q2.y; }
    }
#pragma unroll
    for (int i = 0; i < 8; ++i) {
      float a0 = acc[i][0] * 0.125f, a1 = acc[i][1] * 0.125f;
      st[i][0] += (a0 - st[i][0]) * 0.5f; st[i][1] += (a1 - st[i][1]) * 0.5f;
      float s0 = (st[i][0] >= 0.5f) ? 1.f : 0.f, s1 = (st[i][1] >= 0.5f) ? 1.f : 0.f;
      st[i][0] *= (1.f - s0); st[i][1] *= (1.f - s1);
      u32 two = ((s0 != 0.f) ? 1u : 0u) | ((s1 != 0.f) ? 2u : 0u);
      u32 wmask = two << ((lane & 15) * 2);
      wmask |= __shfl_xor(wmask, 1);
      wmask |= __shfl_xor(wmask, 2);
      wmask |= __shfl_xor(wmask, 4);
      wmask |= __shfl_xor(wmask, 8);
      if ((lane & 15) == 0)
        Om[((size_t)tb * EE + hh * 64 + dh * 32 + dg + i) * 4 + (lane >> 4)] = wmask;
      u32 aw = wmask | __shfl_xor(wmask, 16);
      aw |= __shfl_xor(aw, 32);
      if (lane == 0) sAct[dg + i] = aw ? 1 : 0;
    }
    __syncthreads();
    if (tid < 2) {
      int slot = hh * 4 + dh * 2 + tid;
      int c = 0;
      for (int i = 0; i < 16; ++i)
        if (sAct[tid * 16 + i])
          idsO[((size_t)tb * 32 + slot) * 16 + c++] = (u16)(hh * 64 + dh * 32 + tid * 16 + i);
      cntO[(size_t)tb * 32 + slot] = c;
    }
  }
}

// ---------------- head: mean over V then LIF over t ----------------
__global__ __launch_bounds__(256) void mean_lif(const float* __restrict__ h,
    float* __restrict__ sh)
{
  int i = blockIdx.x * 256 + threadIdx.x;
  float v = 0.f;
#pragma unroll
  for (int t = 0; t < TT; ++t) {
    const float* p = h + ((size_t)t * BB * EE + i) * VV;
    float s = 0.f;
#pragma unroll
    for (int q = 0; q < VV; q += 4) {
      float4 x = *(const float4*)&p[q];
      s += x.x + x.y + x.z + x.w;
    }
    float hm = s * (1.f / 128.f);
    v += (hm - v) * 0.5f;
    float sp = (v >= 1.f) ? 1.f : 0.f;
    sh[(size_t)t * (BB * EE) + i] = sp;
    v *= (1.f - sp);
  }
}

__global__ __launch_bounds__(256) void head_k2(const float* __restrict__ sh,
    const float* __restrict__ hw, const float* __restrict__ hb,
    float* __restrict__ out)
{
  int g = blockIdx.x * 4 + (threadIdx.x >> 6);
  int lane = threadIdx.x & 63;
  if (g >= BB * 11) return;
  int b = g / 11, n = g % 11;
  float s = 0.f;
#pragma unroll
  for (int t = 0; t < TT; ++t) {
    const float* sp = sh + (size_t)t * (BB * EE) + b * EE;
    const float* wp = hw + n * EE;
    float ss = 0.f;
#pragma unroll
    for (int e = 0; e < EE; e += 64) ss += sp[e + lane] * wp[e + lane];
#pragma unroll
    for (int off = 32; off; off >>= 1) ss += __shfl_down(ss, off);
    if (lane == 0) s += ss;
  }
  if (lane == 0) out[g] = s * 0.25f + hb[n];
}

// ---------------- launch ----------------
extern "C" void kernel_launch(void* const* d_in, const int* in_sizes, int n_in,
                              void* d_out, int out_size, void* d_ws, size_t ws_size,
                              hipStream_t stream) {
  const float* x       = (const float*)d_in[0];
  const float* pe_w    = (const float*)d_in[1];
  const float* pe_bn   = (const float*)d_in[2];
  const float* qkvp_w  = (const float*)d_in[3];
  const float* qkvp_bn = (const float*)d_in[4];
  const float* fc1_w   = (const float*)d_in[5];
  const float* fc1_b   = (const float*)d_in[6];
  const float* fc1_bn  = (const float*)d_in[7];
  const float* fc2_w   = (const float*)d_in[8];
  const float* fc2_b   = (const float*)d_in[9];
  const float* fc2_bn  = (const float*)d_in[10];
  const float* head_w  = (const float*)d_in[11];
  const float* head_b  = (const float*)d_in[12];
  float* out = (float*)d_out;

  const size_t NH = (size_t)TT * BB * EE * VV;       // 4194304
  float* ws = (float*)d_ws;
  float* h   = ws;
  float* wq  = h + NH;
  float* w1  = wq + (size_t)6 * 4 * EE * EE;
  float* w2  = w1 + (size_t)6 * HIDC * EE;
  float* sh  = w2 + (size_t)6 * EE * HIDC;
  u32* mIn  = (u32*)(sh + (size_t)TT * BB * EE);
  u32* mQKV = mIn + (size_t)64 * EE * 4;
  u32* mO   = mQKV + (size_t)3 * 64 * EE * 4;
  u32* mMlp = mO + (size_t)64 * EE * 4;
  u32* mHid = mMlp + (size_t)64 * EE * 4;            // 64*HIDC*4
  u32* cntIn = mHid + (size_t)64 * HIDC * 4;         // [64][32]
  u32* cntO  = cntIn + 64 * 32;
  u32* cntM  = cntO + 64 * 32;
  u32* cntH  = cntM + 64 * 32;                       // [64][128]
  u16* idsIn = (u16*)(cntH + 64 * 128);              // [64][32][16]
  u16* idsO  = idsIn + (size_t)64 * 32 * 16;
  u16* idsM  = idsO + (size_t)64 * 32 * 16;
  u16* idsH  = idsM + (size_t)64 * 32 * 16;          // [64][128][16]

  u32* mQ = mQKV;
  u32* mK = mQKV + (size_t)64 * EE * 4;
  u32* mV = mQKV + (size_t)2 * 64 * EE * 4;

  trans_all<<<dim3(1024, 6, 6), 256, 0, stream>>>(qkvp_w, fc1_w, fc2_w, wq, w1, w2);
  pe_lif<<<dim3(BB, EE / 16), 256, 0, stream>>>(x, pe_w, pe_bn, h, mIn, cntIn, idsIn);

  for (int d = 0; d < 6; ++d) {
    const float* bn1p = qkvp_bn + (size_t)d * 4 * 2 * 4 * EE;
    // qkv (z=3): masks -> Q/K/V masks (no list emission; attn scans densely)
    gemm_fused<<<dim3(BB, EE / 16, 3), 256, 0, stream>>>(mIn, cntIn, idsIn, 32,
        wq + (size_t)d * 4 * EE * EE, nullptr, nullptr, mQ, nullptr, nullptr,
        nullptr, bn1p, bn1p + 4 * EE, EE, EE, 1.f,
        (long)EE * EE, (long)64 * EE * 4, (long)2 * 4 * EE);
    attn_fused<<<dim3(BB, 8, 2), 256, 0, stream>>>(mQ, mK, mV, mO, cntO, idsO);
    // proj: + resid -> h; LIF(1) -> mMlp + lists
    gemm_fused<<<dim3(BB, EE / 16, 1), 256, 0, stream>>>(mO, cntO, idsO, 32,
        wq + ((size_t)d * 4 + 3) * EE * EE, h, h, mMlp, cntM, idsM,
        nullptr, bn1p + 3 * (2 * 4 * EE), bn1p + 3 * (2 * 4 * EE) + 4 * EE,
        EE, EE, 1.f, 0, 0, 0);
    // fc1: bias+bn; LIF(1) -> mHid + lists
    gemm_fused<<<dim3(BB, HIDC / 16, 1), 256, 0, stream>>>(mMlp, cntM, idsM, 32,
        w1 + (size_t)d * HIDC * EE, nullptr, nullptr, mHid, cntH, idsH,
        fc1_b + (size_t)d * HIDC, fc1_bn + (size_t)d * 4 * HIDC, nullptr,
        EE, HIDC, 1.f, 0, 0, 0);
    // fc2: bias+bn + resid -> h; LIF(1) -> mIn + lists (next layer input)
    gemm_fused<<<dim3(BB, EE / 16, 1), 256, 0, stream>>>(mHid, cntH, idsH, 128,
        w2 + (size_t)d * EE * HIDC, h, h, mIn, cntIn, idsIn,
        fc2_b + (size_t)d * EE, fc2_bn + (size_t)d * 4 * EE, nullptr,
        HIDC, EE, 1.f, 0, 0, 0);
  }

  mean_lif<<<32, 256, 0, stream>>>(h, sh);
  head_k2<<<44, 256, 0, stream>>>(sh, head_w, head_b, out);
}